// Round 1
// baseline (530.363 us; speedup 1.0000x reference)
//
#include <hip/hip_runtime.h>
#include <hip/hip_bf16.h>
#include <stdint.h>

// Problem constants (fixed by the reference)
#define BB 4096      // batch
#define NN 1024      // generator dim
#define PP 32        // n_params
#define EE 16        // expand ratio
#define NC (NN*EE)   // 16384 output columns

typedef __bf16 bf16x8 __attribute__((ext_vector_type(8)));
typedef float  f32x4  __attribute__((ext_vector_type(4)));

// async global->LDS, 16B per lane. LDS dest must be wave-uniform base; HW
// writes lane i at base + i*16 (guide §5 / m97 / m104).
__device__ __forceinline__ void gl2lds16(const void* g, void* l) {
  __builtin_amdgcn_global_load_lds(
      (const __attribute__((address_space(1))) void*)g,
      (__attribute__((address_space(3))) void*)l,
      16, 0, 0);
}

// ---------------------------------------------------------------------------
// K1: x fp32 -> bf16
__global__ __launch_bounds__(256) void cvt_x_kernel(
    const float* __restrict__ x, __hip_bfloat16* __restrict__ xb) {
  size_t i4 = (size_t)blockIdx.x * 256 + threadIdx.x;   // float4 index
  float4 v = ((const float4*)x)[i4];
  union { __hip_bfloat16 h[4]; ushort4 u; } pk;
  pk.h[0] = __float2bfloat16(v.x);
  pk.h[1] = __float2bfloat16(v.y);
  pk.h[2] = __float2bfloat16(v.z);
  pk.h[3] = __float2bfloat16(v.w);
  *(ushort4*)(xb + i4 * 4) = pk.u;
}

// ---------------------------------------------------------------------------
// K2: Gt[(i*EE+e)*NN + j] = sum_p params[p,e] * T[p, i*NN + j]   (fp32 math,
// bf16 store). One block per i-row; each thread handles 4 consecutive j.
__global__ __launch_bounds__(256) void make_filters(
    const float* __restrict__ params,     // [PP][EE]
    const float* __restrict__ T,          // [PP][NN*NN]
    __hip_bfloat16* __restrict__ Gt) {    // [NC][NN]
  const int tid = threadIdx.x;
  const int i = blockIdx.x;               // 0..NN-1
  const int j = tid * 4;
  const float4* Tv = (const float4*)T;
  const size_t qv = ((size_t)i * NN + j) >> 2;   // float4 index into one p-slab

  float acc[EE][4];
#pragma unroll
  for (int e = 0; e < EE; ++e) {
    acc[e][0] = 0.f; acc[e][1] = 0.f; acc[e][2] = 0.f; acc[e][3] = 0.f;
  }

  for (int p = 0; p < PP; ++p) {
    float4 t = Tv[(size_t)p * (NN * NN / 4) + qv];
#pragma unroll
    for (int e = 0; e < EE; ++e) {
      float w = params[p * EE + e];       // uniform address -> s_load / L1 hit
      acc[e][0] += w * t.x; acc[e][1] += w * t.y;
      acc[e][2] += w * t.z; acc[e][3] += w * t.w;
    }
  }

#pragma unroll
  for (int e = 0; e < EE; ++e) {
    union { __hip_bfloat16 h[4]; ushort4 u; } pk;
    pk.h[0] = __float2bfloat16(acc[e][0]);
    pk.h[1] = __float2bfloat16(acc[e][1]);
    pk.h[2] = __float2bfloat16(acc[e][2]);
    pk.h[3] = __float2bfloat16(acc[e][3]);
    *(ushort4*)&Gt[((size_t)i * EE + e) * NN + j] = pk.u;
  }
}

// ---------------------------------------------------------------------------
// K3: C[b, c] = swish( sum_j A[b,j] * Bt[c,j] )
// A  = x_bf16  [BB][NN] row-major
// Bt = Gt      [NC][NN] row-major (K-major, so A- and B-fragments load alike)
// 128x128 tile, BK=32, 256 threads = 4 waves in 2x2, 4x4 mfma 16x16x32 each.
__global__ __launch_bounds__(256) void gemm_swish(
    const __hip_bfloat16* __restrict__ A,
    const __hip_bfloat16* __restrict__ Bt,
    float* __restrict__ C) {
  __shared__ __hip_bfloat16 As[128 * 32];   // 8 KB, unpadded (global_load_lds)
  __shared__ __hip_bfloat16 Bs[128 * 32];   // 8 KB

  const int tid  = threadIdx.x;
  const int bn   = blockIdx.x;              // 0..127
  const int bm   = blockIdx.y;              // 0..31
  const int wv   = tid >> 6;                // wave 0..3
  const int lane = tid & 63;

  // staging addressing: thread t -> row t/4, elem col (t&3)*8 (16 B)
  const int ldrow = tid >> 2;
  const int ldcol = (tid & 3) * 8;
  const __hip_bfloat16* a0 = A  + ((size_t)bm * 128 + ldrow) * NN + ldcol;
  const __hip_bfloat16* b0 = Bt + ((size_t)bn * 128 + ldrow) * NN + ldcol;
  char* asDst = (char*)As + wv * 1024;      // wave-uniform LDS base
  char* bsDst = (char*)Bs + wv * 1024;

  const int wm   = (wv >> 1) * 64;
  const int wn   = (wv & 1) * 64;
  const int lrow = lane & 15;
  const int lk   = (lane >> 4) * 8;

  f32x4 acc[4][4] = {};

  for (int kt = 0; kt < NN / 32; ++kt) {
    const int k0 = kt * 32;
    __syncthreads();                        // previous iter done reading LDS
    gl2lds16(a0 + k0,            asDst);
    gl2lds16(a0 + 64 * NN + k0,  asDst + 4096);
    gl2lds16(b0 + k0,            bsDst);
    gl2lds16(b0 + 64 * NN + k0,  bsDst + 4096);
    __syncthreads();                        // drains vmcnt -> tiles visible

    bf16x8 af[4], bfr[4];
#pragma unroll
    for (int mt = 0; mt < 4; ++mt)
      af[mt] = *(const bf16x8*)&As[(wm + mt * 16 + lrow) * 32 + lk];
#pragma unroll
    for (int nt = 0; nt < 4; ++nt)
      bfr[nt] = *(const bf16x8*)&Bs[(wn + nt * 16 + lrow) * 32 + lk];

#pragma unroll
    for (int mt = 0; mt < 4; ++mt)
#pragma unroll
      for (int nt = 0; nt < 4; ++nt)
        acc[mt][nt] = __builtin_amdgcn_mfma_f32_16x16x32_bf16(
            af[mt], bfr[nt], acc[mt][nt], 0, 0, 0);
  }

  // epilogue: C/D layout col=lane&15, row=(lane>>4)*4+reg (m89/m91)
  const size_t row0 = (size_t)bm * 128 + wm + (lane >> 4) * 4;
  const size_t col0 = (size_t)bn * 128 + wn + (lane & 15);
#pragma unroll
  for (int mt = 0; mt < 4; ++mt) {
#pragma unroll
    for (int nt = 0; nt < 4; ++nt) {
      const size_t col = col0 + nt * 16;
#pragma unroll
      for (int r = 0; r < 4; ++r) {
        float o = acc[mt][nt][r];
        float s = o / (1.0f + __expf(-o));   // swish
        C[(row0 + mt * 16 + r) * NC + col] = s;
      }
    }
  }
}

// ---------------------------------------------------------------------------
extern "C" void kernel_launch(void* const* d_in, const int* in_sizes, int n_in,
                              void* d_out, int out_size, void* d_ws, size_t ws_size,
                              hipStream_t stream) {
  const float* x      = (const float*)d_in[0];   // [BB][NN]
  const float* params = (const float*)d_in[1];   // [PP][EE]
  const float* T      = (const float*)d_in[2];   // [PP][NN][NN]
  float* out = (float*)d_out;                    // [BB][NN][EE]

  __hip_bfloat16* Gt = (__hip_bfloat16*)d_ws;                       // 32 MB
  __hip_bfloat16* xb = (__hip_bfloat16*)((char*)d_ws + (size_t)NC * NN * 2); // 8 MB

  cvt_x_kernel<<<(BB * NN / 4) / 256, 256, 0, stream>>>(x, xb);
  make_filters<<<NN, 256, 0, stream>>>(params, T, Gt);
  gemm_swish<<<dim3(NC / 128, BB / 128), 256, 0, stream>>>(xb, Gt, out);
}